// Round 3
// baseline (697.281 us; speedup 1.0000x reference)
//
#include <hip/hip_runtime.h>

// Sizes (compile-time constants from the reference)
#define SEQ_LEN 2048
#define EMBD 1024
#define VOCAB 32000
#define RANK 8
#define N_ROWS (2 * SEQ_LEN)      // 4096 token rows (b*T flattened)
#define T_TILE 64                 // token rows per block
#define V4_PER_ROW (VOCAB / 4)    // 8000 float4 per row

// Native vector type: __builtin_nontemporal_store requires a scalar or
// native vector type, not HIP's float4 class. Same 16B layout.
typedef float v4f __attribute__((ext_vector_type(4)));

// ---------------------------------------------------------------------------
// Fully fused kernel: each block owns 64 token rows x 1024 vocab columns.
//
// Phase 1 (low): wave w computes low[w*16 .. w*16+15][0..7] in-block.
//   Redundant across the 32 x-blocks of a row-group, but hidden (16.8 MB)
//   and A (512 KB) are L2/L3-resident, and the extra VALU (~21 us issue
//   time) hides under the 83 us store stream. Removes the separate
//   low_kernel launch + global round-trip + inter-kernel dependency.
//   The 64-row group is bucket-aligned (64 | 128) -> single A slice/block.
//
// Phase 2 (proj): as before — B[r][v..v+3] in registers (8 float4),
//   reused across 64 rows; LDS same-address broadcast for low; coalesced
//   1 KB/wave nontemporal float4 stores (write-once stream, keep out of L2).
//
// Occupancy: fill counters prove write BW saturates at ~10% occupancy, so
// (256,4) is only a spill-safety cap (<=128 VGPR), not a residency target.
// ---------------------------------------------------------------------------
__global__ __launch_bounds__(256, 4) void fused_kernel(
    const float* __restrict__ hidden,
    const float* __restrict__ A,
    const float* __restrict__ B,
    const float* __restrict__ alpha_p,
    float* __restrict__ out)
{
    const int row0 = blockIdx.y * T_TILE;          // first of 64 token rows
    const int t0 = row0 & (SEQ_LEN - 1);
    const int bucket = t0 >> 7;                    // uniform for all 64 rows
    const int tid  = threadIdx.x;
    const int wave = tid >> 6;                     // 0..3
    const int lane = tid & 63;

    __shared__ float slow[T_TILE][RANK];           // 2 KB

    // ---- Phase 1: low for this block's 64 rows (16 rows per wave) ----
    const float alpha = alpha_p[0];
    const float* __restrict__ Ab = A + (size_t)bucket * (EMBD * RANK);
    const float* __restrict__ hbase = hidden + (size_t)(row0 + wave * 16) * EMBD;

    for (int rr = 0; rr < 16; ++rr) {
        const float* h = hbase + (size_t)rr * EMBD;
        float acc[RANK];
#pragma unroll
        for (int r = 0; r < RANK; ++r) acc[r] = 0.f;

#pragma unroll
        for (int q = 0; q < 4; ++q) {
            const int e = q * 256 + lane * 4;      // 64 lanes * 4 = 256 e/q
            const float4 hv = *reinterpret_cast<const float4*>(h + e);
#pragma unroll
            for (int j = 0; j < 4; ++j) {
                const float hval = (&hv.x)[j];
                const float* Ar = Ab + (size_t)(e + j) * RANK;  // 8 floats
                const float4 a0 = *reinterpret_cast<const float4*>(Ar);
                const float4 a1 = *reinterpret_cast<const float4*>(Ar + 4);
                acc[0] += hval * a0.x; acc[1] += hval * a0.y;
                acc[2] += hval * a0.z; acc[3] += hval * a0.w;
                acc[4] += hval * a1.x; acc[5] += hval * a1.y;
                acc[6] += hval * a1.z; acc[7] += hval * a1.w;
            }
        }

        // wave-64 butterfly reduce each rank accumulator
#pragma unroll
        for (int r = 0; r < RANK; ++r) {
#pragma unroll
            for (int off = 32; off > 0; off >>= 1)
                acc[r] += __shfl_down(acc[r], off, 64);
        }
        if (lane == 0) {
#pragma unroll
            for (int r = 0; r < RANK; ++r)
                slow[wave * 16 + rr][r] = alpha * acc[r];
        }
    }
    __syncthreads();

    // ---- Phase 2: project to vocab, stream out ----
    const int v4 = blockIdx.x * 256 + tid;         // float4 index within row
    if (v4 >= V4_PER_ROW) return;                  // after the sync: safe
    const int v = v4 * 4;

    float4 b[RANK];
#pragma unroll
    for (int r = 0; r < RANK; ++r)
        b[r] = *reinterpret_cast<const float4*>(B + (size_t)r * VOCAB + v);

    float* outp = out + (size_t)row0 * VOCAB + v;

#pragma unroll 2
    for (int tt = 0; tt < T_TILE; ++tt) {
        // same-address LDS broadcast, 2x ds_read_b128 per row
        const float4 l0 = *reinterpret_cast<const float4*>(&slow[tt][0]);
        const float4 l1 = *reinterpret_cast<const float4*>(&slow[tt][4]);
        v4f o;
        o.x = l0.x * b[0].x + l0.y * b[1].x + l0.z * b[2].x + l0.w * b[3].x
            + l1.x * b[4].x + l1.y * b[5].x + l1.z * b[6].x + l1.w * b[7].x;
        o.y = l0.x * b[0].y + l0.y * b[1].y + l0.z * b[2].y + l0.w * b[3].y
            + l1.x * b[4].y + l1.y * b[5].y + l1.z * b[6].y + l1.w * b[7].y;
        o.z = l0.x * b[0].z + l0.y * b[1].z + l0.z * b[2].z + l0.w * b[3].z
            + l1.x * b[4].z + l1.y * b[5].z + l1.z * b[6].z + l1.w * b[7].z;
        o.w = l0.x * b[0].w + l0.y * b[1].w + l0.z * b[2].w + l0.w * b[3].w
            + l1.x * b[4].w + l1.y * b[5].w + l1.z * b[6].w + l1.w * b[7].w;
        __builtin_nontemporal_store(o, reinterpret_cast<v4f*>(outp));
        outp += VOCAB;
    }
}

extern "C" void kernel_launch(void* const* d_in, const int* in_sizes, int n_in,
                              void* d_out, int out_size, void* d_ws, size_t ws_size,
                              hipStream_t stream) {
    const float* hidden = (const float*)d_in[0];   // (2, 2048, 1024)
    const float* A      = (const float*)d_in[1];   // (16, 1024, 8)
    const float* B      = (const float*)d_in[2];   // (8, 32000)
    const float* alpha  = (const float*)d_in[3];   // scalar
    float* out = (float*)d_out;                    // (2, 2048, 32000)

    dim3 grid((V4_PER_ROW + 255) / 256, N_ROWS / T_TILE);  // (32, 64)
    fused_kernel<<<grid, 256, 0, stream>>>(hidden, A, B, alpha, out);
}